// Round 9
// baseline (1126.875 us; speedup 1.0000x reference)
//
#include <hip/hip_runtime.h>
#include <hip/hip_bf16.h>
#include <stdint.h>
#include <math.h>

#define NIN_  512
#define NOUT_ 128
#define CIN_  128
#define COUT_ 32
#define MO_   4096   // NOUT*COUT
#define NBT_  32     // build batch (all of B)
#define RB_   16     // routed b-half width
#define NPER_ 4      // n per route chunk
#define NQP_  128    // route n-chunks (NIN_/NPER_)
#define NG_   64     // build n-groups (8 n each) = spart0 partial count

typedef __attribute__((ext_vector_type(4))) float f32x4;

// ---------------------------------------------------------------------------
// K1 (fp32): u[n][bl(32)][mo] = sum_c W1[n][mo][c] * x[bl][n][c]
// PLUS fused iteration-1 s-accumulation: spart0[ng][bl][mo] = sum_{n in group}
// u/128  (c uniform = softmax(0) = 1/128 exactly).
// grid = 1024 = 64 n-groups * 16 mo-tiles(256); block 256 = 4 waves; 8 n/block.
// W staged in LDS as XOR-swizzled float4 units (conflict-free b128).
// ---------------------------------------------------------------------------
__global__ __launch_bounds__(256) void k_build(const float* __restrict__ x,
                                               const float* __restrict__ W1,
                                               float* __restrict__ u,
                                               float* __restrict__ spart0) {
    const int ng  = blockIdx.x >> 4;
    const int mt  = blockIdx.x & 15;
    const int mo0 = mt * 256;
    const int t   = threadIdx.x;
    const int l   = t & 63;
    const int bg  = t >> 6;
    const int cu8 = t & 7;
    const int row = t >> 3;

    __shared__ f32x4 xs4[32 * 32];   // [bl][cu]  16 KB
    __shared__ f32x4 ws4[256 * 8];   // swizzled   32 KB

    float sacc[4][8];
#pragma unroll
    for (int i = 0; i < 4; ++i)
#pragma unroll
        for (int j = 0; j < 8; ++j) sacc[i][j] = 0.f;

    for (int k8 = 0; k8 < 8; ++k8) {
        const int n = ng * 8 + k8;

        __syncthreads();   // previous n's compute done: xs4/ws4 reusable
        for (int k = t; k < NBT_ * 32; k += 256) {
            const int bl = k >> 5;
            const int cu = k & 31;
            xs4[k] = *(const f32x4*)(x + (((size_t)bl * NIN_ + n) * CIN_ + cu * 4));
        }

        f32x4 wr[8];
#pragma unroll
        for (int p = 0; p < 8; ++p) {
            const int ml = row + p * 32;
            wr[p] = *(const f32x4*)(W1 + ((size_t)(n * MO_ + mo0 + ml) * CIN_ + 0 * 32 + cu8 * 4));
        }

        float acc[4][8];
#pragma unroll
        for (int i = 0; i < 4; ++i)
#pragma unroll
            for (int j = 0; j < 8; ++j) acc[i][j] = 0.f;

        for (int ch = 0; ch < 4; ++ch) {
            __syncthreads();           // xs4 staged (ch0) / prev ch compute done
#pragma unroll
            for (int p = 0; p < 8; ++p) {
                const int ml = row + p * 32;
                ws4[ml * 8 + (cu8 ^ (ml & 7))] = wr[p];
            }
            __syncthreads();
            if (ch < 3) {
#pragma unroll
                for (int p = 0; p < 8; ++p) {
                    const int ml = row + p * 32;
                    wr[p] = *(const f32x4*)(W1 + ((size_t)(n * MO_ + mo0 + ml) * CIN_ + (ch + 1) * 32 + cu8 * 4));
                }
            }
#pragma unroll
            for (int c4 = 0; c4 < 8; ++c4) {
                f32x4 wv[4];
#pragma unroll
                for (int i = 0; i < 4; ++i)
                    wv[i] = ws4[(l + i * 64) * 8 + (c4 ^ (l & 7))];
                f32x4 xq[8];
#pragma unroll
                for (int j = 0; j < 8; ++j)
                    xq[j] = xs4[(bg * 8 + j) * 32 + ch * 8 + c4];
#pragma unroll
                for (int i = 0; i < 4; ++i)
#pragma unroll
                    for (int j = 0; j < 8; ++j) {
                        acc[i][j] += wv[i][0] * xq[j][0];
                        acc[i][j] += wv[i][1] * xq[j][1];
                        acc[i][j] += wv[i][2] * xq[j][2];
                        acc[i][j] += wv[i][3] * xq[j][3];
                    }
            }
        }

#pragma unroll
        for (int i = 0; i < 4; ++i)
#pragma unroll
            for (int j = 0; j < 8; ++j) {
                u[((size_t)n * NBT_ + bg * 8 + j) * MO_ + mo0 + i * 64 + l] = acc[i][j];
                sacc[i][j] += acc[i][j];
            }
    }

#pragma unroll
    for (int i = 0; i < 4; ++i)
#pragma unroll
        for (int j = 0; j < 8; ++j)
            spart0[((size_t)ng * NBT_ + bg * 8 + j) * MO_ + mo0 + i * 64 + l] =
                sacc[i][j] * (1.0f / 128.0f);
}

// ---------------------------------------------------------------------------
// K2 fused routing iteration (fp32) — R4/R8 body verbatim, b-half addressing.
// MODE: 1 = first agree (blog=0), 2 = normal
// grid = (RB_/4)*NQP_ = 512; block 256 = 4 waves; wave -> bl = bg*4+w (local
// 0..15); block -> chunk q of NPER_ n's. Global b = bofs + bl.
// Unit layout: f32x4 unit f = j*64+l; m = j*8 + (l>>3); o-quad = l&7.
// Wave-private softmax (shfl only, no LDS/barriers) — post-timing-safe.
// ---------------------------------------------------------------------------
template<int MODE>
__global__ __launch_bounds__(256) void k_route(const float* __restrict__ u,
                                               const float* __restrict__ vws,
                                               float* __restrict__ blog,
                                               float* __restrict__ spart,
                                               int bofs) {
    const int bg  = blockIdx.x & 3;
    const int q   = blockIdx.x >> 2;     // 0..NQP_-1
    const int w   = threadIdx.x >> 6;
    const int l   = threadIdx.x & 63;
    const int bl  = bg * 4 + w;          // local b 0..15
    const int sub = l >> 3;

    f32x4 vr[16];
#pragma unroll
    for (int j = 0; j < 16; ++j)
        vr[j] = *(const f32x4*)(vws + (size_t)bl * MO_ + (j * 64 + l) * 4);

    f32x4 sacc[16];
#pragma unroll
    for (int j = 0; j < 16; ++j) sacc[j] = (f32x4){0.f, 0.f, 0.f, 0.f};

    for (int nn = 0; nn < NPER_; ++nn) {
        const int n = q * NPER_ + nn;
        const f32x4* up = (const f32x4*)(u + ((size_t)n * NBT_ + bofs + bl) * MO_);
        f32x4 ur[16];
#pragma unroll
        for (int j = 0; j < 16; ++j) ur[j] = up[j * 64 + l];

        float* bp = blog + ((size_t)bl * NIN_ + n) * NOUT_;
        float bn[16];
        float mx = -1e30f;
#pragma unroll
        for (int j = 0; j < 16; ++j) {
            float p = vr[j][0] * ur[j][0] + vr[j][1] * ur[j][1]
                    + vr[j][2] * ur[j][2] + vr[j][3] * ur[j][3];
            p += __shfl_xor(p, 1, 64);
            p += __shfl_xor(p, 2, 64);
            p += __shfl_xor(p, 4, 64);
            const float old = (MODE == 1) ? 0.f : bp[j * 8 + sub];
            bn[j] = old + p;
            mx = fmaxf(mx, bn[j]);
        }
        if ((l & 7) == 0) {
#pragma unroll
            for (int j = 0; j < 16; ++j) bp[j * 8 + sub] = bn[j];
        }
        mx = fmaxf(mx, __shfl_xor(mx, 8, 64));
        mx = fmaxf(mx, __shfl_xor(mx, 16, 64));
        mx = fmaxf(mx, __shfl_xor(mx, 32, 64));
        float se = 0.f;
#pragma unroll
        for (int j = 0; j < 16; ++j) {
            bn[j] = expf(bn[j] - mx);
            se += bn[j];
        }
        se += __shfl_xor(se, 8, 64);
        se += __shfl_xor(se, 16, 64);
        se += __shfl_xor(se, 32, 64);
        const float inv = 1.0f / se;
#pragma unroll
        for (int j = 0; j < 16; ++j) {
            const float c = bn[j] * inv;
            sacc[j][0] += c * ur[j][0]; sacc[j][1] += c * ur[j][1];
            sacc[j][2] += c * ur[j][2]; sacc[j][3] += c * ur[j][3];
        }
    }

    f32x4* sp = (f32x4*)(spart + ((size_t)q * RB_ + bl) * MO_);
#pragma unroll
    for (int j = 0; j < 16; ++j) sp[j * 64 + l] = sacc[j];
}

// ---------------------------------------------------------------------------
// K3a: iteration-1 squash from build's spart0 (NG_ partials over all 32 b).
// s[bl][mo] = sum_g spart0[g][bofs+bl][mo]; v = |s|*s/(0.5+s^2) -> vws
// ---------------------------------------------------------------------------
__global__ __launch_bounds__(256) void k_squash0(const float* __restrict__ spart0,
                                                 float* __restrict__ vws, int bofs) {
    const int j  = blockIdx.x * 256 + threadIdx.x;   // bl*MO_ + mo (half-local)
    const int bl = j >> 12;
    const int mo = j & (MO_ - 1);
    float s = 0.f;
#pragma unroll 8
    for (int g = 0; g < NG_; ++g)
        s += spart0[((size_t)g * NBT_ + bofs + bl) * MO_ + mo];
    const float s2 = s * s;
    vws[j] = (sqrtf(s2) / (0.5f + s2)) * s;
}

// ---------------------------------------------------------------------------
// K3: s = sum_q spart (NQP_ partials); v = |s|*s/(0.5+s^2) -> vws
// ---------------------------------------------------------------------------
__global__ __launch_bounds__(256) void k_squash_mid(const float* __restrict__ spart,
                                                    float* __restrict__ vws) {
    const int j = blockIdx.x * 256 + threadIdx.x;   // bl*MO_ + mo (half-local)
    const size_t stride = (size_t)RB_ * MO_;
    float s = 0.f;
#pragma unroll 8
    for (int q = 0; q < NQP_; ++q) s += spart[q * stride + j];
    const float s2 = s * s;
    vws[j] = (sqrtf(s2) / (0.5f + s2)) * s;
}

// ---------------------------------------------------------------------------
// K4: final squash -> poses (fp32, [b][m][o]) + activations [b][m]
// ---------------------------------------------------------------------------
__global__ __launch_bounds__(256) void k_squash_fin(const float* __restrict__ spart,
                                                    float* __restrict__ out,
                                                    int b0) {
    const int j = blockIdx.x * 256 + threadIdx.x;   // bl*MO_ + mo (half-local)
    const size_t stride = (size_t)RB_ * MO_;
    float s = 0.f;
#pragma unroll 8
    for (int q = 0; q < NQP_; ++q) s += spart[q * stride + j];
    const float s2 = s * s;
    const float v = (sqrtf(s2) / (0.5f + s2)) * s;
    out[(size_t)b0 * MO_ + j] = v;

    float v2 = v * v;
#pragma unroll
    for (int d = 16; d >= 1; d >>= 1) v2 += __shfl_xor(v2, d, 64);
    if ((j & 31) == 0) {
        const int bl = j >> 12;
        const int m  = (j >> 5) & 127;
        out[131072 + (size_t)(b0 + bl) * NOUT_ + m] = sqrtf(v2);
    }
}

// ---------------------------------------------------------------------------
extern "C" void kernel_launch(void* const* d_in, const int* in_sizes, int n_in,
                              void* d_out, int out_size, void* d_ws, size_t ws_size,
                              hipStream_t stream) {
    const float* x  = (const float*)d_in[0];
    const float* W1 = (const float*)d_in[1];
    float* out = (float*)d_out;

    char* ws = (char*)d_ws;
    const size_t bytes_u   = (size_t)NBT_ * NIN_ * MO_ * 4;       // 268 MB
    const size_t bytes_sp0 = (size_t)NG_ * NBT_ * MO_ * 4;        // 33.5 MB
    const size_t bytes_bl  = (size_t)RB_ * NIN_ * NOUT_ * 4;      // 4.2 MB
    const size_t bytes_v   = (size_t)RB_ * MO_ * 4;               // 0.26 MB
    const size_t bytes_sp  = (size_t)NQP_ * RB_ * MO_ * 4;        // 33.5 MB
    const size_t need = bytes_u + bytes_sp0 + bytes_bl + bytes_v + bytes_sp;
    if (ws_size < need) return;   // ws observed ≈ 4.3 GB; ample

    float* u      = (float*)(ws);
    float* spart0 = (float*)(ws + bytes_u);
    float* blog   = (float*)(ws + bytes_u + bytes_sp0);
    float* vws    = (float*)(ws + bytes_u + bytes_sp0 + bytes_bl);
    float* spart  = (float*)(ws + bytes_u + bytes_sp0 + bytes_bl + bytes_v);

    // build all 32 b at once (W read exactly once) + fused iteration-1 s-partials
    k_build<<<NG_ * 16, 256, 0, stream>>>(x, W1, u, spart0);

    const int rgrid = (RB_ / 4) * NQP_;   // 512
    const int sgrid = (RB_ * MO_) / 256;  // 256

    // route each 16-b half fully while its 134 MB u-half has L3 affinity
    for (int h = 0; h < 2; ++h) {
        const int bofs = h * RB_;

        // iteration 1's v comes straight from build's fused s-partials
        k_squash0<<<sgrid, 256, 0, stream>>>(spart0, vws, bofs);

        for (int it = 1; it <= 9; ++it) {
            if (it == 1) k_route<1><<<rgrid, 256, 0, stream>>>(u, vws, blog, spart, bofs);
            else         k_route<2><<<rgrid, 256, 0, stream>>>(u, vws, blog, spart, bofs);
            if (it < 9) k_squash_mid<<<sgrid, 256, 0, stream>>>(spart, vws);
            else        k_squash_fin<<<sgrid, 256, 0, stream>>>(spart, out, bofs);
        }
    }
}

// Round 10
// 927.096 us; speedup vs baseline: 1.2155x; 1.2155x over previous
//
#include <hip/hip_runtime.h>
#include <hip/hip_bf16.h>
#include <stdint.h>
#include <math.h>

#define NIN_  512
#define NOUT_ 128
#define CIN_  128
#define COUT_ 32
#define MO_   4096   // NOUT*COUT
#define NBT_  32     // build batch (all of B)
#define RB_   16     // routed b-half width
#define NQ2_  32     // route n-chunks per half (16 n each; 4 n per wave)

typedef __attribute__((ext_vector_type(4))) float f32x4;

// ---------------------------------------------------------------------------
// K1 (fp32): u[n][bl(32)][mo] = sum_c W1[n][mo][c] * x[bl][n][c]
// grid = 8192 = 512 n * 16 mo-tiles(256); block 256 = 4 waves.
// W staged in LDS as XOR-swizzled float4 units (conflict-free b128).
// (R8-verbatim — proven near BW-bound; R9 showed fusing into it regresses)
// ---------------------------------------------------------------------------
__global__ __launch_bounds__(256) void k_build(const float* __restrict__ x,
                                               const float* __restrict__ W1,
                                               float* __restrict__ u) {
    const int n   = blockIdx.x >> 4;
    const int mt  = blockIdx.x & 15;
    const int mo0 = mt * 256;
    const int t   = threadIdx.x;
    const int l   = t & 63;
    const int bg  = t >> 6;

    __shared__ f32x4 xs4[32 * 32];   // [bl][cu]  16 KB
    __shared__ f32x4 ws4[256 * 8];   // swizzled   32 KB

    for (int k = t; k < NBT_ * 32; k += 256) {
        const int bl = k >> 5;
        const int cu = k & 31;
        xs4[k] = *(const f32x4*)(x + (((size_t)bl * NIN_ + n) * CIN_ + cu * 4));
    }

    const int cu8 = t & 7;
    const int row = t >> 3;

    float acc[4][8];
#pragma unroll
    for (int i = 0; i < 4; ++i)
#pragma unroll
        for (int j = 0; j < 8; ++j) acc[i][j] = 0.f;

    f32x4 wr[8];
#pragma unroll
    for (int p = 0; p < 8; ++p) {
        const int ml = row + p * 32;
        wr[p] = *(const f32x4*)(W1 + ((size_t)(n * MO_ + mo0 + ml) * CIN_ + 0 * 32 + cu8 * 4));
    }

    for (int ch = 0; ch < 4; ++ch) {
        __syncthreads();
#pragma unroll
        for (int p = 0; p < 8; ++p) {
            const int ml = row + p * 32;
            ws4[ml * 8 + (cu8 ^ (ml & 7))] = wr[p];
        }
        __syncthreads();
        if (ch < 3) {
#pragma unroll
            for (int p = 0; p < 8; ++p) {
                const int ml = row + p * 32;
                wr[p] = *(const f32x4*)(W1 + ((size_t)(n * MO_ + mo0 + ml) * CIN_ + (ch + 1) * 32 + cu8 * 4));
            }
        }
#pragma unroll
        for (int c4 = 0; c4 < 8; ++c4) {
            f32x4 wv[4];
#pragma unroll
            for (int i = 0; i < 4; ++i)
                wv[i] = ws4[(l + i * 64) * 8 + (c4 ^ (l & 7))];
            f32x4 xq[8];
#pragma unroll
            for (int j = 0; j < 8; ++j)
                xq[j] = xs4[(bg * 8 + j) * 32 + ch * 8 + c4];
#pragma unroll
            for (int i = 0; i < 4; ++i)
#pragma unroll
                for (int j = 0; j < 8; ++j) {
                    acc[i][j] += wv[i][0] * xq[j][0];
                    acc[i][j] += wv[i][1] * xq[j][1];
                    acc[i][j] += wv[i][2] * xq[j][2];
                    acc[i][j] += wv[i][3] * xq[j][3];
                }
        }
    }

#pragma unroll
    for (int i = 0; i < 4; ++i)
#pragma unroll
        for (int j = 0; j < 8; ++j)
            u[((size_t)n * NBT_ + bg * 8 + j) * MO_ + mo0 + i * 64 + l] = acc[i][j];
}

// ---------------------------------------------------------------------------
// K_mean: iteration-1 v directly from u (c uniform = 1/128 exactly):
// s[bl][mo] = (1/128)*sum_n u[n][bofs+bl][mo]; v = |s|*s/(0.5+s^2) -> vws.
// grid = RB_*MO_/256 = 256; deterministic fixed-order n loop; also warms L3
// with this half's u right before its routing iterations.
// ---------------------------------------------------------------------------
__global__ __launch_bounds__(256) void k_mean(const float* __restrict__ u,
                                              float* __restrict__ vws, int bofs) {
    const int j  = blockIdx.x * 256 + threadIdx.x;   // bl*MO_ + mo (half-local)
    const int bl = j >> 12;
    const int mo = j & (MO_ - 1);
    const float* up = u + (size_t)(bofs + bl) * MO_ + mo;
    float s = 0.f;
#pragma unroll 8
    for (int n = 0; n < NIN_; ++n) s += up[(size_t)n * NBT_ * MO_];
    s *= (1.0f / 128.0f);
    const float s2 = s * s;
    vws[j] = (sqrtf(s2) / (0.5f + s2)) * s;
}

// ---------------------------------------------------------------------------
// K2 fused routing iteration (fp32) — R4/R8 inner body verbatim.
// MODE: 1 = first agree (blog=0), 2 = normal
// grid = RB_*NQ2_ = 512; block 256 = 4 waves, ALL on the same bl; wave w takes
// n-chunk qq*4+w (4 n each). End: one-barrier LDS combine of the 4 waves'
// sacc (fixed order w0+w1+w2+w3) -> spart gets 32 partials instead of 128.
// Unit layout: f32x4 unit f = j*64+l; m = j*8 + (l>>3); o-quad = l&7.
// n-loop is wave-private (shfl-only softmax) — post-timing-safe.
// ---------------------------------------------------------------------------
template<int MODE>
__global__ __launch_bounds__(256) void k_route(const float* __restrict__ u,
                                               const float* __restrict__ vws,
                                               float* __restrict__ blog,
                                               float* __restrict__ spart,
                                               int bofs) {
    const int bl  = blockIdx.x & 15;     // local b 0..15
    const int qq  = blockIdx.x >> 4;     // 0..NQ2_-1
    const int w   = threadIdx.x >> 6;
    const int l   = threadIdx.x & 63;
    const int sub = l >> 3;

    __shared__ f32x4 lred[4][16][64];    // 64 KB combine stage

    f32x4 vr[16];
#pragma unroll
    for (int j = 0; j < 16; ++j)
        vr[j] = *(const f32x4*)(vws + (size_t)bl * MO_ + (j * 64 + l) * 4);

    f32x4 sacc[16];
#pragma unroll
    for (int j = 0; j < 16; ++j) sacc[j] = (f32x4){0.f, 0.f, 0.f, 0.f};

    for (int nn = 0; nn < 4; ++nn) {
        const int n = qq * 16 + w * 4 + nn;
        const f32x4* up = (const f32x4*)(u + ((size_t)n * NBT_ + bofs + bl) * MO_);
        f32x4 ur[16];
#pragma unroll
        for (int j = 0; j < 16; ++j) ur[j] = up[j * 64 + l];

        float* bp = blog + ((size_t)bl * NIN_ + n) * NOUT_;
        float bn[16];
        float mx = -1e30f;
#pragma unroll
        for (int j = 0; j < 16; ++j) {
            float p = vr[j][0] * ur[j][0] + vr[j][1] * ur[j][1]
                    + vr[j][2] * ur[j][2] + vr[j][3] * ur[j][3];
            p += __shfl_xor(p, 1, 64);
            p += __shfl_xor(p, 2, 64);
            p += __shfl_xor(p, 4, 64);
            const float old = (MODE == 1) ? 0.f : bp[j * 8 + sub];
            bn[j] = old + p;
            mx = fmaxf(mx, bn[j]);
        }
        if ((l & 7) == 0) {
#pragma unroll
            for (int j = 0; j < 16; ++j) bp[j * 8 + sub] = bn[j];
        }
        mx = fmaxf(mx, __shfl_xor(mx, 8, 64));
        mx = fmaxf(mx, __shfl_xor(mx, 16, 64));
        mx = fmaxf(mx, __shfl_xor(mx, 32, 64));
        float se = 0.f;
#pragma unroll
        for (int j = 0; j < 16; ++j) {
            bn[j] = expf(bn[j] - mx);
            se += bn[j];
        }
        se += __shfl_xor(se, 8, 64);
        se += __shfl_xor(se, 16, 64);
        se += __shfl_xor(se, 32, 64);
        const float inv = 1.0f / se;
#pragma unroll
        for (int j = 0; j < 16; ++j) {
            const float c = bn[j] * inv;
            sacc[j][0] += c * ur[j][0]; sacc[j][1] += c * ur[j][1];
            sacc[j][2] += c * ur[j][2]; sacc[j][3] += c * ur[j][3];
        }
    }

    // in-block combine: all waves store, one barrier, wave w sums units 4w..4w+3
#pragma unroll
    for (int j = 0; j < 16; ++j) lred[w][j][l] = sacc[j];
    __syncthreads();

    f32x4* sp = (f32x4*)(spart + ((size_t)qq * RB_ + bl) * MO_);
#pragma unroll
    for (int jj = 0; jj < 4; ++jj) {
        const int j = w * 4 + jj;
        const f32x4 a0 = lred[0][j][l];
        const f32x4 a1 = lred[1][j][l];
        const f32x4 a2 = lred[2][j][l];
        const f32x4 a3 = lred[3][j][l];
        f32x4 r;
#pragma unroll
        for (int c = 0; c < 4; ++c) r[c] = ((a0[c] + a1[c]) + a2[c]) + a3[c];
        sp[j * 64 + l] = r;
    }
}

// ---------------------------------------------------------------------------
// K3: s = sum_q spart (NQ2_ partials); v = |s|*s/(0.5+s^2) -> vws
// ---------------------------------------------------------------------------
__global__ __launch_bounds__(256) void k_squash_mid(const float* __restrict__ spart,
                                                    float* __restrict__ vws) {
    const int j = blockIdx.x * 256 + threadIdx.x;   // bl*MO_ + mo (half-local)
    const size_t stride = (size_t)RB_ * MO_;
    float s = 0.f;
#pragma unroll 8
    for (int q = 0; q < NQ2_; ++q) s += spart[q * stride + j];
    const float s2 = s * s;
    vws[j] = (sqrtf(s2) / (0.5f + s2)) * s;
}

// ---------------------------------------------------------------------------
// K4: final squash -> poses (fp32, [b][m][o]) + activations [b][m]
// ---------------------------------------------------------------------------
__global__ __launch_bounds__(256) void k_squash_fin(const float* __restrict__ spart,
                                                    float* __restrict__ out,
                                                    int b0) {
    const int j = blockIdx.x * 256 + threadIdx.x;   // bl*MO_ + mo (half-local)
    const size_t stride = (size_t)RB_ * MO_;
    float s = 0.f;
#pragma unroll 8
    for (int q = 0; q < NQ2_; ++q) s += spart[q * stride + j];
    const float s2 = s * s;
    const float v = (sqrtf(s2) / (0.5f + s2)) * s;
    out[(size_t)b0 * MO_ + j] = v;

    float v2 = v * v;
#pragma unroll
    for (int d = 16; d >= 1; d >>= 1) v2 += __shfl_xor(v2, d, 64);
    if ((j & 31) == 0) {
        const int bl = j >> 12;
        const int m  = (j >> 5) & 127;
        out[131072 + (size_t)(b0 + bl) * NOUT_ + m] = sqrtf(v2);
    }
}

// ---------------------------------------------------------------------------
extern "C" void kernel_launch(void* const* d_in, const int* in_sizes, int n_in,
                              void* d_out, int out_size, void* d_ws, size_t ws_size,
                              hipStream_t stream) {
    const float* x  = (const float*)d_in[0];
    const float* W1 = (const float*)d_in[1];
    float* out = (float*)d_out;

    char* ws = (char*)d_ws;
    const size_t bytes_u  = (size_t)NBT_ * NIN_ * MO_ * 4;        // 268 MB
    const size_t bytes_bl = (size_t)RB_ * NIN_ * NOUT_ * 4;       // 4.2 MB
    const size_t bytes_v  = (size_t)RB_ * MO_ * 4;                // 0.26 MB
    const size_t bytes_sp = (size_t)NQ2_ * RB_ * MO_ * 4;         // 8.4 MB
    const size_t need = bytes_u + bytes_bl + bytes_v + bytes_sp;
    if (ws_size < need) return;   // ws observed ≈ 4.3 GB; ample

    float* u     = (float*)(ws);
    float* blog  = (float*)(ws + bytes_u);
    float* vws   = (float*)(ws + bytes_u + bytes_bl);
    float* spart = (float*)(ws + bytes_u + bytes_bl + bytes_v);

    // build all 32 b at once: W read exactly once
    k_build<<<8192, 256, 0, stream>>>(x, W1, u);

    const int rgrid = RB_ * NQ2_;         // 512
    const int sgrid = (RB_ * MO_) / 256;  // 256

    // route each 16-b half fully while its 134 MB u-half stays L3-affine
    for (int h = 0; h < 2; ++h) {
        const int bofs = h * RB_;

        // iteration 1: v from direct mean (uniform c) — also warms L3 with u-half
        k_mean<<<sgrid, 256, 0, stream>>>(u, vws, bofs);

        for (int it = 1; it <= 9; ++it) {
            if (it == 1) k_route<1><<<rgrid, 256, 0, stream>>>(u, vws, blog, spart, bofs);
            else         k_route<2><<<rgrid, 256, 0, stream>>>(u, vws, blog, spart, bofs);
            if (it < 9) k_squash_mid<<<sgrid, 256, 0, stream>>>(spart, vws);
            else        k_squash_fin<<<sgrid, 256, 0, stream>>>(spart, out, bofs);
        }
    }
}